// Round 2
// 1175.459 us; speedup vs baseline: 1.0213x; 1.0213x over previous
//
#include <hip/hip_runtime.h>
#include <math.h>

// Problem constants (fixed by the reference)
#define B_    64
#define LOOKB 32
#define NS    256
#define DM    512
#define DK    128
#define DV    128

// NOTE: Round-1 resubmission of the Round-0 fused kernel. Round-0 bench died
// with an infra error ("MI355X container failed twice") before producing any
// verdict or counters; kernel audited for hang/OOB paths (none found).

__device__ __forceinline__ float sigmoidf_(float x) {
    return 1.0f / (1.0f + expf(-x));
}

// max_lag arrives as a 1-element array; Python int -> int32, but be robust to
// a float32 encoding too (bits of 16.0f are >= 2^23, so this disambiguates).
__device__ __forceinline__ float load_maxlag(const void* p) {
    int vi = *(const int*)p;
    if (vi >= 0 && vi < (1 << 23)) return (float)vi;
    return *(const float*)p;
}

// ---------------------------------------------------------------------------
// Fully fused kernel: one block per batch row b (1024 threads = 16 waves).
// Everything after the shared W_q/W_k/W_v loads is independent per b, and the
// softmax is over NS=256 stocks -> block-local. Phases:
//   0: stage query row + per-stock lag params/gates into LDS
//   1: q[k]  = W_q[k,:] . query[b,:]          (8 lanes per k-row)
//   2: m[d]  = sum_k q[k] * W_k[k,d]          (k-range split over 2 halves)
//   3: score[s] = gate_s * (m . interp_s)/sqrt(DK)   (1 wave = 16 stocks)
//   4: softmax over 256 scores (block-local)
//   5: ctx[d] = sum_s attn_s * interp_s[d]    (4 stock-groups x 256 d-pairs)
//   6: out[b,v] = W_v[v,:] . ctx              (8 lanes per v-row)
// embs traffic: 1 MB (phase 3) + 1 MB (phase 5) per block = 128 MB total.
// Workspace: unused.
// ---------------------------------------------------------------------------
__global__ __launch_bounds__(1024) void k_fused(
    const float* __restrict__ query,
    const float* __restrict__ embs,
    const float* __restrict__ Wq,
    const float* __restrict__ Wk,
    const float* __restrict__ Wv,
    const float* __restrict__ lags,
    const float* __restrict__ gates,
    const void*  __restrict__ maxlag_p,
    float* __restrict__ out)
{
    __shared__ float qe[DM];        // query row
    __shared__ float qv[DK];        // q = query @ Wq^T
    __shared__ float ms[DM];        // m = q @ Wk
    __shared__ float sc[NS];        // scores -> attn (in place)
    __shared__ float gt[NS];        // sigmoid(gates)
    __shared__ int   lfi[NS];
    __shared__ int   lci[NS];
    __shared__ float alf[NS];
    __shared__ float part[4 * DM];  // phase-2 scratch, then ctx partials
    __shared__ float ctxs[DM];
    __shared__ float red[16];

    const int b    = blockIdx.x;
    const int t    = threadIdx.x;
    const int lane = t & 63;
    const int wv   = t >> 6;

    // ---- phase 0: stage query + lag params ----
    if (t < DM) {
        qe[t] = query[b * DM + t];
    } else if (t < DM + NS) {
        const int s = t - DM;
        const float maxlag = load_maxlag(maxlag_p);
        float lag  = sigmoidf_(lags[s]) * maxlag;
        float lf_f = fminf(fmaxf(floorf(lag), 0.0f), (float)(LOOKB - 1));
        float lc_f = fminf(fmaxf(ceilf(lag), 0.0f), (float)(LOOKB - 1));
        lfi[s] = (int)lf_f;
        lci[s] = (int)lc_f;
        alf[s] = lag - lf_f;
        gt[s]  = sigmoidf_(gates[s]);
    }
    __syncthreads();

    // ---- phase 1: qv[r] = Wq[r,:] . qe, 8 lanes per row (r = t>>3) ----
    {
        const int r   = t >> 3;     // 0..127
        const int sub = t & 7;
        const float4* wr = (const float4*)(Wq + (size_t)r * DM);
        float acc = 0.f;
#pragma unroll
        for (int i = 0; i < 16; ++i) {
            float4 w  = wr[sub + i * 8];
            float4 q4 = *(const float4*)(qe + sub * 4 + i * 32);
            acc += w.x * q4.x + w.y * q4.y + w.z * q4.z + w.w * q4.w;
        }
        acc += __shfl_xor(acc, 1, 64);
        acc += __shfl_xor(acc, 2, 64);
        acc += __shfl_xor(acc, 4, 64);
        if (sub == 0) qv[r] = acc;
    }
    __syncthreads();

    // ---- phase 2: ms[d] = sum_k qv[k]*Wk[k,d]; k split over 2 halves ----
    {
        const int d = t & 511;
        const int h = t >> 9;       // 0 or 1
        const float* wkp = Wk + (size_t)(h * 64) * DM + d;
        float acc = 0.f;
#pragma unroll 8
        for (int k = 0; k < 64; ++k)
            acc += qv[h * 64 + k] * wkp[(size_t)k * DM];
        part[t] = acc;              // scratch: [2][512]
    }
    __syncthreads();
    if (t < DM) ms[t] = part[t] + part[t + DM];
    __syncthreads();

    // ---- phase 3: scores; wave wv owns stocks [wv*16, wv*16+16) ----
    {
        const size_t off = (size_t)lane * 8;
        const float4 mr0 = *(const float4*)(ms + off);
        const float4 mr1 = *(const float4*)(ms + off + 4);
        const float* base_b = embs + (size_t)b * LOOKB * NS * DM + off;
#pragma unroll 4
        for (int i = 0; i < 16; ++i) {
            const int s  = (wv << 4) + i;
            const int lf = lfi[s];
            const int lc = lci[s];
            const float a = alf[s];
            const float* pf = base_b + ((size_t)lf * NS + s) * DM;
            const float* pc = base_b + ((size_t)lc * NS + s) * DM;
            float4 f0 = *(const float4*)(pf);
            float4 f1 = *(const float4*)(pf + 4);
            float4 c0 = *(const float4*)(pc);
            float4 c1 = *(const float4*)(pc + 4);
            float acc = mr0.x * (f0.x + a * (c0.x - f0.x))
                      + mr0.y * (f0.y + a * (c0.y - f0.y))
                      + mr0.z * (f0.z + a * (c0.z - f0.z))
                      + mr0.w * (f0.w + a * (c0.w - f0.w))
                      + mr1.x * (f1.x + a * (c1.x - f1.x))
                      + mr1.y * (f1.y + a * (c1.y - f1.y))
                      + mr1.z * (f1.z + a * (c1.z - f1.z))
                      + mr1.w * (f1.w + a * (c1.w - f1.w));
#pragma unroll
            for (int o = 32; o; o >>= 1)
                acc += __shfl_xor(acc, o, 64);
            if (lane == 0)
                sc[s] = gt[s] * acc * 0.0883883476483184405f; // 1/sqrt(128)
        }
    }
    __syncthreads();

    // ---- phase 4: block softmax over sc[0..255] ----
    {
        const float v = (t < NS) ? sc[t] : -INFINITY;
        float mx = v;
#pragma unroll
        for (int o = 32; o; o >>= 1)
            mx = fmaxf(mx, __shfl_xor(mx, o, 64));
        if (lane == 0) red[wv] = mx;
        __syncthreads();
        const float gmx = fmaxf(fmaxf(red[0], red[1]), fmaxf(red[2], red[3]));
        const float e = (t < NS) ? expf(v - gmx) : 0.f;
        float sm = e;
#pragma unroll
        for (int o = 32; o; o >>= 1)
            sm += __shfl_xor(sm, o, 64);
        __syncthreads();                    // red reuse
        if (lane == 0) red[wv] = sm;
        __syncthreads();
        const float tot = red[0] + red[1] + red[2] + red[3];
        if (t < NS) sc[t] = e / tot;        // sc now holds attn
    }
    __syncthreads();

    // ---- phase 5: ctx[d] = sum_s attn_s * interp_s[d] ----
    {
        const int c  = t & 255;             // d-pair index
        const int g  = t >> 8;              // stock group 0..3
        const int d0 = c * 2;
        float ax = 0.f, ay = 0.f;
        const float* base_b = embs + (size_t)b * LOOKB * NS * DM + d0;
#pragma unroll 4
        for (int i = 0; i < 64; ++i) {
            const int s  = (g << 6) + i;
            const int lf = lfi[s];
            const int lc = lci[s];
            const float a = alf[s];
            const float w = sc[s];
            const float2 ef = *(const float2*)(base_b + ((size_t)lf * NS + s) * DM);
            const float2 ec = *(const float2*)(base_b + ((size_t)lc * NS + s) * DM);
            ax += w * (ef.x + a * (ec.x - ef.x));
            ay += w * (ef.y + a * (ec.y - ef.y));
        }
        float2 o; o.x = ax; o.y = ay;
        *(float2*)(part + g * DM + d0) = o;
    }
    __syncthreads();
    if (t < DM)
        ctxs[t] = part[t] + part[DM + t] + part[2 * DM + t] + part[3 * DM + t];
    __syncthreads();

    // ---- phase 6: out[b,v] = Wv[v,:] . ctx, 8 lanes per row ----
    {
        const int r   = t >> 3;     // 0..127
        const int sub = t & 7;
        const float4* wr = (const float4*)(Wv + (size_t)r * DM);
        float acc = 0.f;
#pragma unroll
        for (int i = 0; i < 16; ++i) {
            float4 w  = wr[sub + i * 8];
            float4 c4 = *(const float4*)(ctxs + sub * 4 + i * 32);
            acc += w.x * c4.x + w.y * c4.y + w.z * c4.z + w.w * c4.w;
        }
        acc += __shfl_xor(acc, 1, 64);
        acc += __shfl_xor(acc, 2, 64);
        acc += __shfl_xor(acc, 4, 64);
        if (sub == 0) out[b * DV + r] = acc;
    }
}

// ---------------------------------------------------------------------------
extern "C" void kernel_launch(void* const* d_in, const int* in_sizes, int n_in,
                              void* d_out, int out_size, void* d_ws, size_t ws_size,
                              hipStream_t stream) {
    const float* query = (const float*)d_in[0];   // (B, DM)
    const float* embs  = (const float*)d_in[1];   // (B, LOOKB, NS, DM)
    const float* Wq    = (const float*)d_in[2];   // (DK, DM)
    const float* Wk    = (const float*)d_in[3];   // (DK, DM)
    const float* Wv    = (const float*)d_in[4];   // (DV, DM)
    const float* lags  = (const float*)d_in[5];   // (NS,)
    const float* gates = (const float*)d_in[6];   // (NS,)
    const void*  maxlag_p = d_in[7];              // scalar

    float* out = (float*)d_out;                   // (B, DV) fp32
    (void)in_sizes; (void)n_in; (void)out_size; (void)d_ws; (void)ws_size;

    k_fused<<<B_, 1024, 0, stream>>>(query, embs, Wq, Wk, Wv,
                                     lags, gates, maxlag_p, out);
}